// Round 1
// baseline (1890.857 us; speedup 1.0000x reference)
//
#include <hip/hip_runtime.h>
#include <cmath>

#define HW 307200        // 480*640
#define NB 8             // batches
#define NBASE 63         // input basis channels (ones channel prepended -> 64)
#define NSLAB (HW/64)    // 4800 pixel slabs of 64

// ---- workspace layout (floats) ----
#define XTX_OFF 0                       // 8 * 64*64
#define XTY_OFF (NB*64*64)              // 8 * 64
#define YTY_OFF (XTY_OFF + NB*64)       // 8
#define NC_OFF  (YTY_OFF + NB)          // 8
#define ZERO_FLOATS (NC_OFF + NB)       // zero-init region ends here
#define MP_OFF  ZERO_FLOATS             // 8 * 64*64 (upper-tri M, diag halved, /beta)
#define WV_OFF  (MP_OFF + NB*64*64)     // 8 * 64

// ---- output layout (floats) ----
#define OUT_W   (NB*HW)                 // weights after logits
#define OUT_VAR (OUT_W + NB*64)         // var after weights

__device__ __forceinline__ bool finitef(float x) {
    // fast-math-proof isfinite: exponent bits not all ones
    return (__float_as_uint(x) & 0x7f800000u) != 0x7f800000u;
}

// ============================================================
// Kernel 1: masked Gram XtX (64x64), Xty (64), yty, N per batch
// LDS slab: 64 pixels x 64 channels, transposed [p][ch], stride 68
// 256 threads = 4 waves; wave w owns pixels 16w..16w+15; each lane an
// 8x8 register tile of C. Reduction via atomicAdd into ws.
// ============================================================
__global__ __launch_bounds__(256) void gram_kernel(
    const float* __restrict__ bases, const float* __restrict__ targets,
    float* __restrict__ ws)
{
    __shared__ float tile[64*68];
    __shared__ float sy[64];
    __shared__ float sm[64];

    const int t  = threadIdx.x;
    const int b  = blockIdx.y;
    const int wv = t >> 6;          // wave id 0..3
    const int l  = t & 63;          // lane
    const int ti = l >> 3, tj = l & 7;
    const int p_stage = t & 63;     // staging pixel
    const int cg = t >> 6;          // staging channel group (wave-uniform)

    float acc[8][8];
#pragma unroll
    for (int i = 0; i < 8; i++)
#pragma unroll
        for (int j = 0; j < 8; j++) acc[i][j] = 0.f;

    float acc_xty = 0.f;
    float acc_yty = 0.f, acc_n = 0.f;

    const float* basesb = bases + (long)b * NBASE * HW;
    const float* targb  = targets + (long)b * HW;

    for (int s = blockIdx.x; s < NSLAB; s += gridDim.x) {
        const int pix0 = s * 64;
        if (t < 64) {
            float yv = targb[pix0 + t];
            bool fin = finitef(yv);
            float mf = fin ? 1.f : 0.f;
            float yf = fin ? yv : 0.f;
            sy[t] = yf; sm[t] = mf;
            acc_yty = fmaf(yf, yf, acc_yty);
            acc_n  += mf;
        }
        __syncthreads();
        {
            const float mf = sm[p_stage];
#pragma unroll
            for (int c = cg; c < 64; c += 4) {
                float v;
                if (c == 0) v = mf;  // masked ones channel (wave-uniform branch)
                else        v = basesb[(long)(c - 1) * HW + pix0 + p_stage] * mf;
                tile[p_stage * 68 + c] = v;
            }
        }
        __syncthreads();
#pragma unroll 2
        for (int pp = 0; pp < 16; ++pp) {
            const int p = wv * 16 + pp;
            const float4 r0 = *(const float4*)&tile[p*68 + 8*ti];
            const float4 r1 = *(const float4*)&tile[p*68 + 8*ti + 4];
            const float4 c0 = *(const float4*)&tile[p*68 + 8*tj];
            const float4 c1 = *(const float4*)&tile[p*68 + 8*tj + 4];
            const float rr[8] = {r0.x,r0.y,r0.z,r0.w,r1.x,r1.y,r1.z,r1.w};
            const float cc[8] = {c0.x,c0.y,c0.z,c0.w,c1.x,c1.y,c1.z,c1.w};
#pragma unroll
            for (int i = 0; i < 8; i++)
#pragma unroll
                for (int j = 0; j < 8; j++)
                    acc[i][j] = fmaf(rr[i], cc[j], acc[i][j]);
            // Xty: lane l owns channel l for this wave's pixel stripe
            acc_xty = fmaf(sy[p], tile[p*68 + l], acc_xty);
        }
        __syncthreads();
    }

    float* XtX = ws + XTX_OFF + b * 4096;
#pragma unroll
    for (int i = 0; i < 8; i++)
#pragma unroll
        for (int j = 0; j < 8; j++)
            atomicAdd(&XtX[(8*ti + i) * 64 + 8*tj + j], acc[i][j]);
    atomicAdd(&ws[XTY_OFF + b*64 + l], acc_xty);
    if (t < 64) {  // wave 0: reduce yty, N
#pragma unroll
        for (int off = 32; off; off >>= 1) {
            acc_yty += __shfl_down(acc_yty, off, 64);
            acc_n   += __shfl_down(acc_n,   off, 64);
        }
        if (t == 0) {
            atomicAdd(&ws[YTY_OFF + b], acc_yty);
            atomicAdd(&ws[NC_OFF  + b], acc_n);
        }
    }
}

// ============================================================
// Kernel 2: per batch (8 blocks x 64 threads = 1 wave):
// Cholesky(XtX), explicit inverse, w = XtX^-1 Xty,
// E_d = yty - 2 w.Xty + w.XtX.w, EM beta loop (done-latched),
// emit weights to d_out, and Mp (upper-tri, diag*0.5, * 1/beta) + w to ws.
// ============================================================
__global__ __launch_bounds__(64) void solve_kernel(
    float* __restrict__ ws, float* __restrict__ out)
{
    __shared__ float A[64*65];
    __shared__ float W[64*65];
    __shared__ float d0[64], xty[64], wv_s[64];

    const int b = blockIdx.x;
    const int t = threadIdx.x;
    const float* XtX = ws + XTX_OFF + b * 4096;

    for (int j = 0; j < 64; j++) A[t*65 + j] = XtX[t*64 + j];
    xty[t] = ws[XTY_OFF + b*64 + t];
    d0[t]  = A[t*65 + t];
    const float yty = ws[YTY_OFF + b];
    const float Nc  = ws[NC_OFF  + b];
    __syncthreads();

    // Cholesky (lower), upper triangle keeps original XtX
    for (int k = 0; k < 64; k++) {
        float akk = A[k*65 + k];
        __syncthreads();
        float dk = sqrtf(akk);
        if (t == k)      A[k*65 + k] = dk;
        else if (t > k)  A[t*65 + k] = A[t*65 + k] / dk;
        __syncthreads();
        if (t > k) {
            float ltk = A[t*65 + k];
            for (int j = k + 1; j <= t; j++)
                A[t*65 + j] -= ltk * A[j*65 + k];
        }
        __syncthreads();
    }

    // inverse: thread t solves column t of (L L^T)^-1
    for (int i = 0; i < 64; i++) {
        float s = (i == t) ? 1.f : 0.f;
        for (int j = 0; j < i; j++) s = fmaf(-A[i*65 + j], W[j*65 + t], s);
        W[i*65 + t] = s / A[i*65 + i];
    }
    for (int i = 63; i >= 0; i--) {
        float s = W[i*65 + t];
        for (int j = i + 1; j < 64; j++) s = fmaf(-A[j*65 + i], W[j*65 + t], s);
        W[i*65 + t] = s / A[i*65 + i];
    }
    __syncthreads();

    // w = Minv @ Xty
    float wt = 0.f;
    for (int j = 0; j < 64; j++) wt = fmaf(W[t*65 + j], xty[j], wt);
    wv_s[t] = wt;
    __syncthreads();

    // E_d = yty - 2 w.Xty + w.(XtX w)   (XtX from upper triangle + saved diag)
    float qt = 0.f;
    for (int j = 0; j < 64; j++) {
        float x = (j > t) ? A[t*65 + j] : ((j == t) ? d0[t] : A[j*65 + t]);
        qt = fmaf(x, wv_s[j], qt);
    }
    float r1 = wt * xty[t];
    float r2 = wt * qt;
#pragma unroll
    for (int off = 32; off; off >>= 1) {
        r1 += __shfl_down(r1, off, 64);
        r2 += __shfl_down(r2, off, 64);
    }
    r1 = __shfl(r1, 0, 64);
    r2 = __shfl(r2, 0, 64);
    const float E_d = yty - 2.f * r1 + r2;

    // EM beta loop, faithful to reference latch order
    float beta0 = sqrtf(Nc);
    float beta  = beta0;
    bool  done  = false;
#pragma unroll
    for (int it = 0; it < 5; ++it) {
        float Tr_d = 64.f / beta;
        float beta_new = Nc / (E_d + Tr_d);
        bool conv = fabsf(beta_new / beta0 - 1.f) < 0.02f;
        if (!done) { beta = beta_new; beta0 = beta_new; }
        done = done || conv;
    }
    const float ib = 1.f / beta;

    out[OUT_W + b*64 + t] = wt;
    ws[WV_OFF + b*64 + t] = wt;
    float* Mp = ws + MP_OFF + b * 4096;
    for (int j = 0; j < 64; j++) {
        float v = (j < t) ? 0.f : ((j == t) ? 0.5f : 1.f) * W[t*65 + j] * ib;
        Mp[t*64 + j] = v;
    }
}

// ============================================================
// Kernel 3: per pixel: pred = w.b (ones channel incl),
// var = 2 * sum_i b_i * sum_{j>=i} Mp[i][j] b_j
// M/w accessed via wave-uniform indices -> scalar loads (SGPR operands),
// b held in 64 VGPRs via fully unrolled triangular loops.
// ============================================================
__global__ __launch_bounds__(256) void predvar_kernel(
    const float* __restrict__ bases, const float* __restrict__ ws,
    float* __restrict__ out)
{
    const int b   = blockIdx.y;
    const int pix = blockIdx.x * 256 + threadIdx.x;
    const float* __restrict__ Mp = ws + MP_OFF + b * 4096;
    const float* __restrict__ wb = ws + WV_OFF + b * 64;
    const float* basesb = bases + (long)b * NBASE * HW + pix;

    float bv[64];
    bv[0] = 1.f;
#pragma unroll
    for (int c = 1; c < 64; c++) bv[c] = basesb[(long)(c - 1) * HW];

    float pred = wb[0];
#pragma unroll
    for (int c = 1; c < 64; c++) pred = fmaf(wb[c], bv[c], pred);

    float var2 = 0.f;
#pragma unroll
    for (int i = 0; i < 64; i++) {
        float si = 0.f;
#pragma unroll
        for (int j = i; j < 64; j++) si = fmaf(Mp[i*64 + j], bv[j], si);
        var2 = fmaf(si, bv[i], var2);
    }

    out[(long)b * HW + pix] = pred;
    out[OUT_VAR + (long)b * HW + pix] = 2.f * var2;
}

extern "C" void kernel_launch(void* const* d_in, const int* in_sizes, int n_in,
                              void* d_out, int out_size, void* d_ws, size_t ws_size,
                              hipStream_t stream)
{
    const float* bases   = (const float*)d_in[0];
    const float* targets = (const float*)d_in[1];
    float* out = (float*)d_out;
    float* ws  = (float*)d_ws;

    // zero the accumulator region (ws is poisoned 0xAA before every call)
    hipMemsetAsync(d_ws, 0, ZERO_FLOATS * sizeof(float), stream);

    gram_kernel<<<dim3(128, NB), 256, 0, stream>>>(bases, targets, ws);
    solve_kernel<<<NB, 64, 0, stream>>>(ws, out);
    predvar_kernel<<<dim3(HW / 256, NB), 256, 0, stream>>>(bases, ws, out);
}